// Round 4
// baseline (7610.099 us; speedup 1.0000x reference)
//
#include <hip/hip_runtime.h>
#include <hip/hip_fp16.h>

#define BB 128
#define II 64
#define SS 2048
#define HH 128
#define GG 512   // 4*H
#define OO 64

typedef _Float16 f16x2 __attribute__((ext_vector_type(2)));
union F4H { float4 f4; f16x2 h[4]; };

__device__ __forceinline__ f16x2 pack2(float a, float b) {
    f16x2 r; r.x = (_Float16)a; r.y = (_Float16)b; return r;
}

__device__ __forceinline__ float dot2(f16x2 w, f16x2 v, float c) {
#if __has_builtin(__builtin_amdgcn_fdot2)
    return __builtin_amdgcn_fdot2(w, v, c, false);
#else
    return fmaf((float)w.x, (float)v.x, fmaf((float)w.y, (float)v.y, c));
#endif
}

__device__ __forceinline__ float tanh_f(float v) {
    float a = fabsf(v);
    float e = __expf(-2.0f * a);
    float r = (1.0f - e) * __builtin_amdgcn_rcpf(1.0f + e);
    return v < 0.0f ? -r : r;
}

// quad broadcast: every lane gets lane (quad_base + C)'s value. Pure-VALU DPP.
template<int C>
__device__ __forceinline__ float qb(float v) {
    return __int_as_float(__builtin_amdgcn_mov_dpp(
        __float_as_int(v), 0x55 * C, 0xF, 0xF, true));
}
// DPP row rotate-LEFT by N within each 16-lane row: lane i <- lane (i+N)&15.
// (row_ror:N gives lane i <- lane (i-N)&15 — that direction broke R2.)
template<int N>
__device__ __forceinline__ float rolN(float v) {
    return __int_as_float(__builtin_amdgcn_mov_dpp(
        __float_as_int(v), 0x120 + (16 - N), 0xF, 0xF, true));
}

// LDS-only barrier: avoids __syncthreads()'s vmcnt(0) drain of in-flight
// global loads/stores. LDS ordering (hb/xib/hib/xt) is all we need.
__device__ __forceinline__ void barrier_lds() {
    asm volatile("s_waitcnt lgkmcnt(0)\n\ts_barrier" ::: "memory");
}

// One block per batch element, 512 threads.
// Quad-gate layout: thread j owns gate column (j&3)*128 + (j>>2); gate
// combination and state update are DPP quad-broadcasts (no LDS/barrier).
// 2 raw (lgkm-only) barriers per step. x staged in 16-step LDS tiles.
// NEW (R4): x@Wx_out computed in a per-tile burst -> per-lane wxf LDS
// reads drop 16x (was the largest LDS-pipe consumer). Results in
// xwg[16][512]: thread j writes/reads ONLY its own column (no barrier,
// no race, conflict-free lane-consecutive access).
__global__ void __launch_bounds__(512)
__attribute__((amdgpu_waves_per_eu(2)))
nlstm_scan(
    const float* __restrict__ x,
    const float* __restrict__ Wx_out, const float* __restrict__ Wh_out,
    const float* __restrict__ b_out,
    const float* __restrict__ Wx_in, const float* __restrict__ Wh_in,
    const float* __restrict__ b_in,
    const float* __restrict__ W_lin, const float* __restrict__ b_lin,
    float* __restrict__ out)
{
    const int b = blockIdx.x;
    const int j = threadIdx.x;
    const int u = j >> 2;          // hidden unit
    const int g = j & 3;           // gate: 0=i 1=f 2=o 3=g
    const int jcol = g * HH + u;   // column of the 512-wide gate matrices

    __shared__ __align__(16) float4 wxf[8 * 512];      // Wx_out fp16, 64 KB
    __shared__ __align__(16) float  xwg[16][GG];       // xW + b_out, 32 KB
    // x tile: 16 timesteps, row = timestep, entry m = (x[2m][t],x[2m+1][t]).
    __shared__ __align__(16) f16x2 xt[2][16][36];      // 4.5 KB
    __shared__ __align__(16) f16x2 hb[HH / 2];         // h fp16
    __shared__ __align__(16) f16x2 xib[HH / 2];        // x_in fp16
    __shared__ __align__(16) f16x2 hib[HH / 2];        // h_in fp16

    // ---- register/AGPR-resident fp16 weights (column jcol) ----
    f16x2 who[HH / 2];   // Wh_out col jcol
    f16x2 wxi[HH / 2];   // Wx_in  col jcol
    f16x2 whi[HH / 2];   // Wh_in  col jcol
#pragma unroll
    for (int m = 0; m < HH / 2; ++m)
        who[m] = pack2(Wh_out[(2 * m) * GG + jcol], Wh_out[(2 * m + 1) * GG + jcol]);
#pragma unroll
    for (int m = 0; m < HH / 2; ++m)
        wxi[m] = pack2(Wx_in[(2 * m) * GG + jcol], Wx_in[(2 * m + 1) * GG + jcol]);
#pragma unroll
    for (int m = 0; m < HH / 2; ++m)
        whi[m] = pack2(Wh_in[(2 * m) * GG + jcol], Wh_in[(2 * m + 1) * GG + jcol]);

    const float bo  = b_out[jcol];
    const float bi2 = b_in[jcol];
    const int   pn = j >> 3;       // projection output column
    const int   ps = j & 7;        // projection k-slice
    const float bl = b_lin[pn];

    // W_lin -> registers (2 chunks of row pn: k = 16*ps .. 16*ps+16)
    F4H wl[2];
#pragma unroll
    for (int q = 0; q < 2; ++q) {
        const int c = 2 * ps + q;
#pragma unroll
        for (int r = 0; r < 4; ++r)
            wl[q].h[r] = pack2(W_lin[pn * HH + 8 * c + 2 * r],
                               W_lin[pn * HH + 8 * c + 2 * r + 1]);
    }

    // Wx_out column jcol -> LDS slot j, fp16 (lane-consecutive b128 reads)
#pragma unroll
    for (int c = 0; c < 8; ++c) {
        F4H w4;
#pragma unroll
        for (int q = 0; q < 4; ++q)
            w4.h[q] = pack2(Wx_out[(8 * c + 2 * q) * GG + jcol],
                            Wx_out[(8 * c + 2 * q + 1) * GG + jcol]);
        wxf[c * 512 + j] = w4.f4;
    }

    const float* xrow = x + (size_t)b * II * SS;   // x[b,i,t] = xrow[i*SS + t]
    float* orow = out + (size_t)b * SS * OO;

    // x tile slot for this thread: entry xm of timestep-row xtl
    const int xm  = j >> 4;    // 0..31
    const int xtl = j & 15;    // 0..15
    const float* xg0 = xrow + (size_t)(2 * xm) * SS + xtl;
    const float* xg1 = xrow + (size_t)(2 * xm + 1) * SS + xtl;

    // tile 0 -> buffer 0
    xt[0][xtl][xm] = pack2(xg0[0], xg1[0]);
    if (j < HH / 2) hb[j] = pack2(0.f, 0.f);
    __syncthreads();   // startup: full sync ok

    float c_reg = 0.f, cn_reg = 0.f;   // quad-replicated cell states (fp32)

    const float4* hb4 = (const float4*)hb;
    const float4* xi4 = (const float4*)xib;
    const float4* hi4 = (const float4*)hib;
    const bool isT = (g == 3);

    float pr0 = 0.f, pr1 = 0.f;        // x-tile prefetch registers

#pragma unroll 1
    for (int t = 0; t < SS; ++t) {
        const int stl = t & 15;        // step's row in the tile
        const int tb  = (t >> 4) & 1;  // current tile buffer

        if (stl == 0) {
            // ---- prefetch next 16-step x tile (HBM latency hides under burst) ----
            const int Tn = (t + 16 < SS) ? t + 16 : t;  // clamp: dead reload
            pr0 = xg0[Tn];
            pr1 = xg1[Tn];

            // ---- xW burst: xwg[tt][j] = bo + x_tile[tt] . Wx_out[:,jcol] ----
            // Reads each wxf chunk ONCE per tile (was once per STEP).
            // Thread j writes only xwg[*][j] and reads only xwg[*][j]:
            // no cross-thread traffic, no barrier needed.
            float xa16[16];
#pragma unroll
            for (int tt = 0; tt < 16; ++tt) xa16[tt] = bo;
#pragma unroll
            for (int c = 0; c < 8; ++c) {
                F4H wu; wu.f4 = wxf[c * 512 + j];
#pragma unroll
                for (int tt = 0; tt < 16; ++tt) {
                    F4H xu; xu.f4 = ((const float4*)&xt[tb][tt][0])[c];
                    xa16[tt] = dot2(wu.h[0], xu.h[0], xa16[tt]);
                    xa16[tt] = dot2(wu.h[1], xu.h[1], xa16[tt]);
                    xa16[tt] = dot2(wu.h[2], xu.h[2], xa16[tt]);
                    xa16[tt] = dot2(wu.h[3], xu.h[3], xa16[tt]);
                }
            }
#pragma unroll
            for (int tt = 0; tt < 16; ++tt) xwg[tt][j] = xa16[tt];
        }

        // ---- outer gates: xW (precomputed) + h@Wh_out, 4-way ILP ----
        float a0 = xwg[stl][j];        // x-part + bias (own column, no race)
        float a1 = 0.f, a2 = 0.f, a3 = 0.f;
#pragma unroll
        for (int c = 0; c < 16; ++c) {
            F4H hu; hu.f4 = hb4[c];
            a0 = dot2(who[4 * c + 0], hu.h[0], a0);
            a1 = dot2(who[4 * c + 1], hu.h[1], a1);
            a2 = dot2(who[4 * c + 2], hu.h[2], a2);
            a3 = dot2(who[4 * c + 3], hu.h[3], a3);
        }
        float acc = (a0 + a1) + (a2 + a3);

        // unified activation: g<3 sigmoid, g==3 tanh = 2*sigm(2x)-1
        float ap = isT ? 2.f * acc : acc;
        float s  = __builtin_amdgcn_rcpf(1.f + __expf(-ap));
        float av = isT ? fmaf(2.f, s, -1.f) : s;

        // gate combination inside the quad (no LDS, no barrier)
        float vi = qb<0>(av), vf = qb<1>(av), vo = qb<2>(av), vg = qb<3>(av);
        float x_in    = vi * vg;        // i * g
        float h_in    = vf * c_reg;     // f * c
        float o_outer = vo;             // kept for h_new

        // ---- projection of h_{t-1} (pipelined; hb still holds h_{t-1}) ----
        float p0 = 0.f, p1 = 0.f;
        {
            F4H hu0; hu0.f4 = hb4[2 * ps];
            F4H hu1; hu1.f4 = hb4[2 * ps + 1];
            p0 = dot2(wl[0].h[0], hu0.h[0], p0);
            p1 = dot2(wl[0].h[1], hu0.h[1], p1);
            p0 = dot2(wl[0].h[2], hu0.h[2], p0);
            p1 = dot2(wl[0].h[3], hu0.h[3], p1);
            p0 = dot2(wl[1].h[0], hu1.h[0], p0);
            p1 = dot2(wl[1].h[1], hu1.h[1], p1);
            p0 = dot2(wl[1].h[2], hu1.h[2], p0);
            p1 = dot2(wl[1].h[3], hu1.h[3], p1);
        }
        float p = p0 + p1;
        p += rolN<4>(p);   // lane i += lane i+4  (ps==0 lanes stay in-group)
        p += rolN<2>(p);
        p += rolN<1>(p);
        if (ps == 0 && t > 0) orow[(size_t)(t - 1) * OO + pn] = p + bl;

        // write x_in/h_in pairs (lane j=8k packs units 2k,2k+1 via DPP rol4)
        float xin_n = rolN<4>(x_in);
        float hin_n = rolN<4>(h_in);
        if ((j & 7) == 0) {
            xib[u >> 1] = pack2(x_in, xin_n);
            hib[u >> 1] = pack2(h_in, hin_n);
        }
        barrier_lds();   // B_a: xib/hib visible; hb readers done before write

        // ---- inner gates: 8 accumulators (chain depth 16) ----
        float c0 = bi2, c1 = 0.f, c2 = 0.f, c3 = 0.f;
        float d0 = 0.f, d1 = 0.f, d2 = 0.f, d3 = 0.f;
#pragma unroll
        for (int c = 0; c < 16; ++c) {
            F4H xu; xu.f4 = xi4[c];
            c0 = dot2(wxi[4 * c + 0], xu.h[0], c0);
            c1 = dot2(wxi[4 * c + 1], xu.h[1], c1);
            c2 = dot2(wxi[4 * c + 2], xu.h[2], c2);
            c3 = dot2(wxi[4 * c + 3], xu.h[3], c3);
        }
#pragma unroll
        for (int c = 0; c < 16; ++c) {
            F4H hu; hu.f4 = hi4[c];
            d0 = dot2(whi[4 * c + 0], hu.h[0], d0);
            d1 = dot2(whi[4 * c + 1], hu.h[1], d1);
            d2 = dot2(whi[4 * c + 2], hu.h[2], d2);
            d3 = dot2(whi[4 * c + 3], hu.h[3], d3);
        }
        float acc2 = ((c0 + c1) + (c2 + c3)) + ((d0 + d1) + (d2 + d3));

        float ap2 = isT ? 2.f * acc2 : acc2;
        float s2  = __builtin_amdgcn_rcpf(1.f + __expf(-ap2));
        float av2 = isT ? fmaf(2.f, s2, -1.f) : s2;

        // state update inside the quad (no LDS, no barrier)
        float ii = qb<0>(av2), fi = qb<1>(av2), oi = qb<2>(av2), gg = qb<3>(av2);
        float cn_new = fmaf(fi, cn_reg, ii * gg);
        cn_reg = cn_new;
        float c_new = oi * tanh_f(cn_new);
        c_reg = c_new;
        float h_new = o_outer * tanh_f(c_new);

        float hn_n = rolN<4>(h_new);
        if ((j & 7) == 0) hb[u >> 1] = pack2(h_new, hn_n);
        // stash prefetched tile into the other buffer (last read pre-B_a)
        if (stl == 0) xt[tb ^ 1][xtl][xm] = pack2(pr0, pr1);
        barrier_lds();   // B_b: h_t (+ new tile) visible
    }

    // ---- final projection: out[S-1] from h_{S-1} ----
    {
        float p0 = 0.f, p1 = 0.f;
        F4H hu0; hu0.f4 = hb4[2 * ps];
        F4H hu1; hu1.f4 = hb4[2 * ps + 1];
        p0 = dot2(wl[0].h[0], hu0.h[0], p0);
        p1 = dot2(wl[0].h[1], hu0.h[1], p1);
        p0 = dot2(wl[0].h[2], hu0.h[2], p0);
        p1 = dot2(wl[0].h[3], hu0.h[3], p1);
        p0 = dot2(wl[1].h[0], hu1.h[0], p0);
        p1 = dot2(wl[1].h[1], hu1.h[1], p1);
        p0 = dot2(wl[1].h[2], hu1.h[2], p0);
        p1 = dot2(wl[1].h[3], hu1.h[3], p1);
        float p = p0 + p1;
        p += rolN<4>(p);
        p += rolN<2>(p);
        p += rolN<1>(p);
        if (ps == 0) orow[(size_t)(SS - 1) * OO + pn] = p + bl;
    }
}

extern "C" void kernel_launch(void* const* d_in, const int* in_sizes, int n_in,
                              void* d_out, int out_size, void* d_ws, size_t ws_size,
                              hipStream_t stream) {
    (void)in_sizes; (void)n_in; (void)d_ws; (void)ws_size; (void)out_size;
    const float* x      = (const float*)d_in[0];
    const float* Wx_out = (const float*)d_in[1];
    const float* Wh_out = (const float*)d_in[2];
    const float* b_out  = (const float*)d_in[3];
    const float* Wx_in  = (const float*)d_in[4];
    const float* Wh_in  = (const float*)d_in[5];
    const float* b_in   = (const float*)d_in[6];
    const float* W_lin  = (const float*)d_in[7];
    const float* b_lin  = (const float*)d_in[8];
    float* out = (float*)d_out;

    nlstm_scan<<<dim3(BB), dim3(512), 0, stream>>>(
        x, Wx_out, Wh_out, b_out, Wx_in, Wh_in, b_in, W_lin, b_lin, out);
}